// Round 1
// baseline (39.978 us; speedup 1.0000x reference)
//
#include <hip/hip_runtime.h>
#include <hip/hip_bf16.h>
#include <math.h>

// ======================= compile-time Wigner 3j =======================
namespace cw {

struct CD { double re, im; };
constexpr CD cmul(CD a, CD b) { return CD{a.re*b.re - a.im*b.im, a.re*b.im + a.im*b.re}; }
constexpr CD cadd(CD a, CD b) { return CD{a.re + b.re, a.im + b.im}; }

template <int N> struct ArrD { double v[N] {}; };
template <int N> struct ArrC { CD v[N] {}; };

constexpr double csqrt_(double x) {
  if (x <= 0.0) return 0.0;
  double g = x > 1.0 ? x : 1.0;
  for (int i = 0; i < 200; ++i) g = 0.5 * (g + x / g);
  return g;
}

constexpr ArrD<32> make_fact() {
  ArrD<32> f{};
  f.v[0] = 1.0;
  for (int i = 1; i < 32; ++i) f.v[i] = f.v[i - 1] * (double)i;
  return f;
}
constexpr ArrD<32> FACT = make_fact();
static_assert(FACT.v[5] == 120.0, "factorial sanity");

constexpr double su2_cg(int j1, int j2, int j3, int m1, int m2, int m3) {
  if (m3 != m1 + m2) return 0.0;
  int vmin = 0;
  if (-j1 + j2 + m3 > vmin) vmin = -j1 + j2 + m3;
  if (-j1 + m1 > vmin) vmin = -j1 + m1;
  int vmax = j2 + j3 + m1;
  if (j3 - j1 + j2 < vmax) vmax = j3 - j1 + j2;
  if (j3 + m3 < vmax) vmax = j3 + m3;
  const double c = csqrt_((2.0 * j3 + 1.0) * FACT.v[j3 + j1 - j2] * FACT.v[j3 - j1 + j2] *
                          FACT.v[j1 + j2 - j3] * FACT.v[j3 + m3] * FACT.v[j3 - m3] /
                          (FACT.v[j1 + j2 + j3 + 1] * FACT.v[j1 - m1] * FACT.v[j1 + m1] *
                           FACT.v[j2 - m2] * FACT.v[j2 + m2]));
  double s = 0.0;
  for (int v = vmin; v <= vmax; ++v) {
    const double sg = ((v + j2 + m2) % 2 == 0) ? 1.0 : -1.0;
    s += sg * FACT.v[j2 + j3 + m1 - v] * FACT.v[j1 - m1 + v] /
         (FACT.v[v] * FACT.v[j3 - j1 + j2 - v] * FACT.v[j3 + m3 - v] * FACT.v[v + j1 - j2 - m3]);
  }
  return c * s;
}

template <int L> constexpr ArrC<(2 * L + 1) * (2 * L + 1)> real_basis() {
  constexpr int n = 2 * L + 1;
  ArrC<n * n> q{};
  const double s = 1.0 / csqrt_(2.0);
  for (int m = -L; m < 0; ++m) {
    q.v[(L + m) * n + (L - m)] = CD{s, 0.0};
    q.v[(L + m) * n + (L + m)] = CD{0.0, -s};
  }
  q.v[L * n + L] = CD{1.0, 0.0};
  for (int m = 1; m <= L; ++m) {
    const double sg = (m % 2 == 0) ? 1.0 : -1.0;
    q.v[(L + m) * n + (L + m)] = CD{sg * s, 0.0};
    q.v[(L + m) * n + (L - m)] = CD{0.0, sg * s};
  }
  CD ph = CD{1.0, 0.0};
  if (L % 4 == 1) ph = CD{0.0, -1.0};
  if (L % 4 == 2) ph = CD{-1.0, 0.0};
  if (L % 4 == 3) ph = CD{0.0, 1.0};
  for (int i = 0; i < n * n; ++i) q.v[i] = cmul(ph, q.v[i]);
  return q;
}

// C'[i,j,k] = Re( sum_{a,b,c} Q1[a,i] Q2[b,j] conj(Q3)[k,c] CG[a,b,c] ), normalized.
template <int L1, int L2, int L3>
constexpr ArrD<(2 * L1 + 1) * (2 * L2 + 1) * (2 * L3 + 1)> w3j_real() {
  constexpr int n1 = 2 * L1 + 1, n2 = 2 * L2 + 1, n3 = 2 * L3 + 1;
  const ArrC<n1 * n1> Q1 = real_basis<L1>();
  const ArrC<n2 * n2> Q2 = real_basis<L2>();
  const ArrC<n3 * n3> Q3 = real_basis<L3>();
  // T1[a,b,k] = sum_c conj(Q3[k,c]) * CG[a,b,c]  (CG nonzero only at c = L3 + m1 + m2)
  ArrC<n1 * n2 * n3> T1{};
  for (int a = 0; a < n1; ++a)
    for (int b = 0; b < n2; ++b) {
      const int m3 = (a - L1) + (b - L2);
      if (m3 < -L3 || m3 > L3) continue;
      const int c = L3 + m3;
      const double cg = su2_cg(L1, L2, L3, a - L1, b - L2, m3);
      if (cg == 0.0) continue;
      for (int k = 0; k < n3; ++k) {
        const CD q = Q3.v[k * n3 + c];
        if (q.re != 0.0 || q.im != 0.0)
          T1.v[(a * n2 + b) * n3 + k] = cadd(T1.v[(a * n2 + b) * n3 + k], CD{q.re * cg, -q.im * cg});
      }
    }
  // T2[a,j,k] = sum_b Q2[b,j] * T1[a,b,k]
  ArrC<n1 * n2 * n3> T2{};
  for (int a = 0; a < n1; ++a)
    for (int b = 0; b < n2; ++b)
      for (int j = 0; j < n2; ++j) {
        const CD q = Q2.v[b * n2 + j];
        if (q.re == 0.0 && q.im == 0.0) continue;
        for (int k = 0; k < n3; ++k) {
          const CD t = T1.v[(a * n2 + b) * n3 + k];
          if (t.re != 0.0 || t.im != 0.0)
            T2.v[(a * n2 + j) * n3 + k] = cadd(T2.v[(a * n2 + j) * n3 + k], cmul(q, t));
        }
      }
  // OUT[i,j,k] = Re( sum_a Q1[a,i] * T2[a,j,k] )
  ArrD<n1 * n2 * n3> O{};
  for (int a = 0; a < n1; ++a)
    for (int i = 0; i < n1; ++i) {
      const CD q = Q1.v[a * n1 + i];
      if (q.re == 0.0 && q.im == 0.0) continue;
      for (int j = 0; j < n2; ++j)
        for (int k = 0; k < n3; ++k) {
          const CD t = T2.v[(a * n2 + j) * n3 + k];
          O.v[(i * n2 + j) * n3 + k] += q.re * t.re - q.im * t.im;
        }
    }
  double nrm2 = 0.0;
  for (int e = 0; e < n1 * n2 * n3; ++e) nrm2 += O.v[e] * O.v[e];
  const double inv = 1.0 / csqrt_(nrm2);
  for (int e = 0; e < n1 * n2 * n3; ++e) O.v[e] *= inv;
  return O;
}

constexpr ArrD<81>  W440 = w3j_real<4, 4, 0>();
constexpr ArrD<405> W442 = w3j_real<4, 4, 2>();
constexpr ArrD<169> W660 = w3j_real<6, 6, 0>();
constexpr ArrD<845> W662 = w3j_real<6, 6, 2>();
constexpr ArrD<585> W462 = w3j_real<4, 6, 2>();
constexpr ArrD<585> W642 = w3j_real<6, 4, 2>();
constexpr ArrD<75>  W221 = w3j_real<2, 2, 1>();

} // namespace cw

// ======================= kernel =======================
// Math notes (why this is equivalent to the reference):
//  * C441/C661 are antisymmetric in (I,J); contracted with f x f (same single
//    channel) they are exactly 0 => v==0, gv==0 => only the tt path of layer 2
//    survives. The fp32 noise (~1e-6 abs) this drops is ~1e-5 of |vec|.
//  * alpha/beta/gamma/R are invariant to any uniform positive scaling of vec,
//    so the constants _C_SILU, _C_SIG, _C2, _CT2 cancel. Only _C0 (inside the
//    sigmoid argument) is kept. s1/scal/hs are dead.
__global__ __launch_bounds__(256) void geo_euler(
    const float* __restrict__ feat,
    const float* __restrict__ w44s2, const float* __restrict__ w66s2,
    const float* __restrict__ w44t, const float* __restrict__ w46t,
    const float* __restrict__ w64t, const float* __restrict__ w66t,
    const float* __restrict__ wtt,
    float* __restrict__ out, int B)
{
  const int b = blockIdx.x * 256 + threadIdx.x;
  if (b >= B) return;
  const float* f = feat + (size_t)b * 22;

  float f4[9], f6[13];
#pragma unroll
  for (int i = 0; i < 9; ++i) f4[i] = f[i];
#pragma unroll
  for (int i = 0; i < 13; ++i) f6[i] = f[9 + i];

  float q44 = 0.f, q66 = 0.f;
  float T44[5] = {}, T66[5] = {}, T46[5] = {}, T64[5] = {};

  // l=4 x l=4 (symmetrized pair loop; exact fold of C[I,J]+C[J,I])
#pragma unroll
  for (int I = 0; I < 9; ++I)
#pragma unroll
    for (int J = I; J < 9; ++J) {
      const float p = f4[I] * f4[J];
      {
        const float c = (I == J) ? (float)cw::W440.v[I * 9 + J]
                                 : (float)(cw::W440.v[I * 9 + J] + cw::W440.v[J * 9 + I]);
        if (c != 0.f) q44 = fmaf(c, p, q44);
      }
#pragma unroll
      for (int K = 0; K < 5; ++K) {
        const float c = (I == J) ? (float)cw::W442.v[(I * 9 + J) * 5 + K]
                                 : (float)(cw::W442.v[(I * 9 + J) * 5 + K] + cw::W442.v[(J * 9 + I) * 5 + K]);
        if (c != 0.f) T44[K] = fmaf(c, p, T44[K]);
      }
    }

  // l=6 x l=6
#pragma unroll
  for (int I = 0; I < 13; ++I)
#pragma unroll
    for (int J = I; J < 13; ++J) {
      const float p = f6[I] * f6[J];
      {
        const float c = (I == J) ? (float)cw::W660.v[I * 13 + J]
                                 : (float)(cw::W660.v[I * 13 + J] + cw::W660.v[J * 13 + I]);
        if (c != 0.f) q66 = fmaf(c, p, q66);
      }
#pragma unroll
      for (int K = 0; K < 5; ++K) {
        const float c = (I == J) ? (float)cw::W662.v[(I * 13 + J) * 5 + K]
                                 : (float)(cw::W662.v[(I * 13 + J) * 5 + K] + cw::W662.v[(J * 13 + I) * 5 + K]);
        if (c != 0.f) T66[K] = fmaf(c, p, T66[K]);
      }
    }

  // l=4 x l=6 (both orders, no symmetry assumption: W642 indexed [b6][a4][K])
#pragma unroll
  for (int a = 0; a < 9; ++a)
#pragma unroll
    for (int bb = 0; bb < 13; ++bb) {
      const float p = f4[a] * f6[bb];
#pragma unroll
      for (int K = 0; K < 5; ++K) {
        const float c46 = (float)cw::W462.v[(a * 13 + bb) * 5 + K];
        if (c46 != 0.f) T46[K] = fmaf(c46, p, T46[K]);
        const float c64 = (float)cw::W642.v[(bb * 9 + a) * 5 + K];
        if (c64 != 0.f) T64[K] = fmaf(c64, p, T64[K]);
      }
    }

  // gates (channels 8..15 of s2; C_SIG dropped — uniform scale)
  float g[8];
#pragma unroll
  for (int u = 0; u < 8; ++u) {
    const float s = 0.70710678118654752f * fmaf(w44s2[8 + u], q44, w66s2[8 + u] * q66);
    g[u] = 1.f / (1.f + __expf(-s));
  }

  // gated tensor features (C2 dropped — uniform scale)
  float gt[8][5];
#pragma unroll
  for (int w = 0; w < 8; ++w) {
    const float a0 = w44t[w], a1 = w46t[w], a2 = w64t[w], a3 = w66t[w];
#pragma unroll
    for (int K = 0; K < 5; ++K)
      gt[w][K] = g[w] * (a0 * T44[K] + a1 * T46[K] + a2 * T64[K] + a3 * T66[K]);
  }

  // layer 2, tt path only: vec[w,K] = sum_{u!=v} wtt[u,v,w] * (gt_u^T C221_K gt_v)
  float v0[3] = {}, v1[3] = {};
#pragma unroll
  for (int v = 0; v < 8; ++v) {
    float av[15] = {}; // av[K*5+I] = sum_J C221[I,J,K] * gt[v][J]
#pragma unroll
    for (int I = 0; I < 5; ++I)
#pragma unroll
      for (int J = 0; J < 5; ++J)
#pragma unroll
        for (int K = 0; K < 3; ++K) {
          const float c = (float)cw::W221.v[(I * 5 + J) * 3 + K];
          if (c != 0.f) av[K * 5 + I] = fmaf(c, gt[v][J], av[K * 5 + I]);
        }
#pragma unroll
    for (int u = 0; u < 8; ++u) {
      if (u == v) continue; // diagonal is exactly 0 (antisymmetric form)
      float Bk0 = 0.f, Bk1 = 0.f, Bk2 = 0.f;
#pragma unroll
      for (int I = 0; I < 5; ++I) {
        Bk0 = fmaf(gt[u][I], av[0 * 5 + I], Bk0);
        Bk1 = fmaf(gt[u][I], av[1 * 5 + I], Bk1);
        Bk2 = fmaf(gt[u][I], av[2 * 5 + I], Bk2);
      }
      const float wt0 = wtt[(u * 8 + v) * 2 + 0];
      const float wt1 = wtt[(u * 8 + v) * 2 + 1];
      v0[0] = fmaf(wt0, Bk0, v0[0]); v0[1] = fmaf(wt0, Bk1, v0[1]); v0[2] = fmaf(wt0, Bk2, v0[2]);
      v1[0] = fmaf(wt1, Bk0, v1[0]); v1[1] = fmaf(wt1, Bk1, v1[1]); v1[2] = fmaf(wt1, Bk2, v1[2]);
    }
  }

  // Gram-Schmidt frame + Euler angles
  const float n0 = sqrtf(v0[0] * v0[0] + v0[1] * v0[1] + v0[2] * v0[2]);
  const float i0 = 1.f / fmaxf(n0, 1e-6f);
  const float z0 = v0[0] * i0, z1 = v0[1] * i0, z2 = v0[2] * i0;
  const float dot = z0 * v1[0] + z1 * v1[1] + z2 * v1[2];
  const float xv0 = v1[0] - dot * z0, xv1 = v1[1] - dot * z1, xv2 = v1[2] - dot * z2;
  const float nx = sqrtf(xv0 * xv0 + xv1 * xv1 + xv2 * xv2);
  const float ix = 1.f / fmaxf(nx, 1e-6f);
  const float x0 = xv0 * ix, x1 = xv1 * ix, x2 = xv2 * ix;
  const float y0 = z1 * x2 - z2 * x1;
  const float y1 = z2 * x0 - z0 * x2;
  const float y2 = z0 * x1 - z1 * x0;

  const float r22 = fminf(fmaxf(z2, -1.f), 1.f);
  const float beta = acosf(r22);
  const bool safe = fabsf(sinf(beta)) > 1e-6f;
  const float alpha = safe ? atan2f(z1, z0) : 0.f;
  const float gamma = safe ? atan2f(y2, -x2) : atan2f(-y0, y1);

  out[b] = alpha;
  out[B + b] = beta;
  out[2 * (size_t)B + b] = gamma;
  float* Ro = out + 3 * (size_t)B + (size_t)b * 9;
  Ro[0] = x0; Ro[1] = y0; Ro[2] = z0;
  Ro[3] = x1; Ro[4] = y1; Ro[5] = z1;
  Ro[6] = x2; Ro[7] = y2; Ro[8] = z2;
}

extern "C" void kernel_launch(void* const* d_in, const int* in_sizes, int n_in,
                              void* d_out, int out_size, void* d_ws, size_t ws_size,
                              hipStream_t stream) {
  (void)n_in; (void)out_size; (void)d_ws; (void)ws_size;
  const float* feat  = (const float*)d_in[0];
  const float* w44s2 = (const float*)d_in[3];
  const float* w66s2 = (const float*)d_in[4];
  const float* w44t  = (const float*)d_in[7];
  const float* w46t  = (const float*)d_in[8];
  const float* w64t  = (const float*)d_in[9];
  const float* w66t  = (const float*)d_in[10];
  const float* wtt   = (const float*)d_in[16];
  float* out = (float*)d_out;
  const int B = in_sizes[0] / 22;
  geo_euler<<<(B + 255) / 256, 256, 0, stream>>>(feat, w44s2, w66s2, w44t, w46t, w64t, w66t, wtt, out, B);
}

// Round 2
// 19.642 us; speedup vs baseline: 2.0353x; 2.0353x over previous
//
#include <hip/hip_runtime.h>
#include <hip/hip_bf16.h>
#include <math.h>

// ======================= compile-time Wigner 3j =======================
namespace cw {

struct CD { double re, im; };
constexpr CD cmul(CD a, CD b) { return CD{a.re*b.re - a.im*b.im, a.re*b.im + a.im*b.re}; }
constexpr CD cadd(CD a, CD b) { return CD{a.re + b.re, a.im + b.im}; }

template <int N> struct ArrD { double v[N] {}; };
template <int N> struct ArrC { CD v[N] {}; };

constexpr double csqrt_(double x) {
  if (x <= 0.0) return 0.0;
  double g = x > 1.0 ? x : 1.0;
  for (int i = 0; i < 200; ++i) g = 0.5 * (g + x / g);
  return g;
}

constexpr ArrD<32> make_fact() {
  ArrD<32> f{};
  f.v[0] = 1.0;
  for (int i = 1; i < 32; ++i) f.v[i] = f.v[i - 1] * (double)i;
  return f;
}
constexpr ArrD<32> FACT = make_fact();
static_assert(FACT.v[5] == 120.0, "factorial sanity");

constexpr double su2_cg(int j1, int j2, int j3, int m1, int m2, int m3) {
  if (m3 != m1 + m2) return 0.0;
  int vmin = 0;
  if (-j1 + j2 + m3 > vmin) vmin = -j1 + j2 + m3;
  if (-j1 + m1 > vmin) vmin = -j1 + m1;
  int vmax = j2 + j3 + m1;
  if (j3 - j1 + j2 < vmax) vmax = j3 - j1 + j2;
  if (j3 + m3 < vmax) vmax = j3 + m3;
  const double c = csqrt_((2.0 * j3 + 1.0) * FACT.v[j3 + j1 - j2] * FACT.v[j3 - j1 + j2] *
                          FACT.v[j1 + j2 - j3] * FACT.v[j3 + m3] * FACT.v[j3 - m3] /
                          (FACT.v[j1 + j2 + j3 + 1] * FACT.v[j1 - m1] * FACT.v[j1 + m1] *
                           FACT.v[j2 - m2] * FACT.v[j2 + m2]));
  double s = 0.0;
  for (int v = vmin; v <= vmax; ++v) {
    const double sg = ((v + j2 + m2) % 2 == 0) ? 1.0 : -1.0;
    s += sg * FACT.v[j2 + j3 + m1 - v] * FACT.v[j1 - m1 + v] /
         (FACT.v[v] * FACT.v[j3 - j1 + j2 - v] * FACT.v[j3 + m3 - v] * FACT.v[v + j1 - j2 - m3]);
  }
  return c * s;
}

template <int L> constexpr ArrC<(2 * L + 1) * (2 * L + 1)> real_basis() {
  constexpr int n = 2 * L + 1;
  ArrC<n * n> q{};
  const double s = 1.0 / csqrt_(2.0);
  for (int m = -L; m < 0; ++m) {
    q.v[(L + m) * n + (L - m)] = CD{s, 0.0};
    q.v[(L + m) * n + (L + m)] = CD{0.0, -s};
  }
  q.v[L * n + L] = CD{1.0, 0.0};
  for (int m = 1; m <= L; ++m) {
    const double sg = (m % 2 == 0) ? 1.0 : -1.0;
    q.v[(L + m) * n + (L + m)] = CD{sg * s, 0.0};
    q.v[(L + m) * n + (L - m)] = CD{0.0, sg * s};
  }
  CD ph = CD{1.0, 0.0};
  if (L % 4 == 1) ph = CD{0.0, -1.0};
  if (L % 4 == 2) ph = CD{-1.0, 0.0};
  if (L % 4 == 3) ph = CD{0.0, 1.0};
  for (int i = 0; i < n * n; ++i) q.v[i] = cmul(ph, q.v[i]);
  return q;
}

template <int L1, int L2, int L3>
constexpr ArrD<(2 * L1 + 1) * (2 * L2 + 1) * (2 * L3 + 1)> w3j_real() {
  constexpr int n1 = 2 * L1 + 1, n2 = 2 * L2 + 1, n3 = 2 * L3 + 1;
  const ArrC<n1 * n1> Q1 = real_basis<L1>();
  const ArrC<n2 * n2> Q2 = real_basis<L2>();
  const ArrC<n3 * n3> Q3 = real_basis<L3>();
  ArrC<n1 * n2 * n3> T1{};
  for (int a = 0; a < n1; ++a)
    for (int b = 0; b < n2; ++b) {
      const int m3 = (a - L1) + (b - L2);
      if (m3 < -L3 || m3 > L3) continue;
      const int c = L3 + m3;
      const double cg = su2_cg(L1, L2, L3, a - L1, b - L2, m3);
      if (cg == 0.0) continue;
      for (int k = 0; k < n3; ++k) {
        const CD q = Q3.v[k * n3 + c];
        if (q.re != 0.0 || q.im != 0.0)
          T1.v[(a * n2 + b) * n3 + k] = cadd(T1.v[(a * n2 + b) * n3 + k], CD{q.re * cg, -q.im * cg});
      }
    }
  ArrC<n1 * n2 * n3> T2{};
  for (int a = 0; a < n1; ++a)
    for (int b = 0; b < n2; ++b)
      for (int j = 0; j < n2; ++j) {
        const CD q = Q2.v[b * n2 + j];
        if (q.re == 0.0 && q.im == 0.0) continue;
        for (int k = 0; k < n3; ++k) {
          const CD t = T1.v[(a * n2 + b) * n3 + k];
          if (t.re != 0.0 || t.im != 0.0)
            T2.v[(a * n2 + j) * n3 + k] = cadd(T2.v[(a * n2 + j) * n3 + k], cmul(q, t));
        }
      }
  ArrD<n1 * n2 * n3> O{};
  for (int a = 0; a < n1; ++a)
    for (int i = 0; i < n1; ++i) {
      const CD q = Q1.v[a * n1 + i];
      if (q.re == 0.0 && q.im == 0.0) continue;
      for (int j = 0; j < n2; ++j)
        for (int k = 0; k < n3; ++k) {
          const CD t = T2.v[(a * n2 + j) * n3 + k];
          O.v[(i * n2 + j) * n3 + k] += q.re * t.re - q.im * t.im;
        }
    }
  double nrm2 = 0.0;
  for (int e = 0; e < n1 * n2 * n3; ++e) nrm2 += O.v[e] * O.v[e];
  const double inv = 1.0 / csqrt_(nrm2);
  for (int e = 0; e < n1 * n2 * n3; ++e) O.v[e] *= inv;
  return O;
}

constexpr ArrD<81>  W440 = w3j_real<4, 4, 0>();
constexpr ArrD<405> W442 = w3j_real<4, 4, 2>();
constexpr ArrD<169> W660 = w3j_real<6, 6, 0>();
constexpr ArrD<845> W662 = w3j_real<6, 6, 2>();
constexpr ArrD<585> W462 = w3j_real<4, 6, 2>();
constexpr ArrD<585> W642 = w3j_real<6, 4, 2>();
constexpr ArrD<75>  W221 = w3j_real<2, 2, 1>();

// C642[b,a,k] == C462[a,b,k] (CG swap symmetry: j1+j2-j3 = 8 even) — verified:
constexpr bool sym642() {
  for (int a = 0; a < 9; ++a)
    for (int b = 0; b < 13; ++b)
      for (int k = 0; k < 5; ++k) {
        const double d = W642.v[(b * 9 + a) * 5 + k] - W462.v[(a * 13 + b) * 5 + k];
        if (d > 1e-9 || d < -1e-9) return false;
      }
  return true;
}
static_assert(sym642(), "W642 != W462^T — basis fold invalid");

} // namespace cw

// ======================= pre-kernel: weight-only coefficients =======================
// vec[K,w] = sum_{p<q} B_K(T_p,T_q) * S_w(pq),
// S_w(pq) = sum_{u<v} c[w][pq][uv] * g_u g_v,
// c = (wtt[u,v,w]-wtt[v,u,w]) * (a_p[u] a_q[v] - a_p[v] a_q[u]),
// basis p in {T44, T46(=T64), T66}, a_0=w44t, a_1=w46t+w64t, a_2=w66t.
__global__ void precoef(const float* __restrict__ w44t, const float* __restrict__ w46t,
                        const float* __restrict__ w64t, const float* __restrict__ w66t,
                        const float* __restrict__ wtt, float* __restrict__ cc) {
  const int t = threadIdx.x;
  if (t >= 168) return;
  const int w = t / 84;
  const int pq = (t % 84) / 28;
  const int uvi = t % 28;
  int U = 0, V = 1, idx = 0;
#pragma unroll
  for (int u = 0; u < 8; ++u)
#pragma unroll
    for (int v = u + 1; v < 8; ++v) {
      if (idx == uvi) { U = u; V = v; }
      ++idx;
    }
  const int p = (pq == 2) ? 1 : 0;
  const int q = (pq == 0) ? 1 : 2;
  auto aw = [&](int pp, int uu) -> float {
    return pp == 0 ? w44t[uu] : (pp == 1 ? (w46t[uu] + w64t[uu]) : w66t[uu]);
  };
  const float Aw = wtt[(U * 8 + V) * 2 + w] - wtt[(V * 8 + U) * 2 + w];
  cc[t] = Aw * (aw(p, U) * aw(q, V) - aw(p, V) * aw(q, U));
}

// ======================= fast atan2 (minimax, err ~1e-6 rad) =======================
__device__ __forceinline__ float fatan2(float y, float x) {
  const float ax = fabsf(x), ay = fabsf(y);
  const float mx = fmaxf(ax, ay), mn = fminf(ax, ay);
  const float a = mn * __builtin_amdgcn_rcpf(fmaxf(mx, 1e-38f));
  const float s = a * a;
  float r = fmaf(s, fmaf(s, fmaf(s, fmaf(s, fmaf(s, -0.0117212f, 0.05265332f),
                                         -0.11643287f), 0.19354346f), -0.33262347f), 0.99997726f);
  r *= a;
  if (ay > ax) r = 1.57079637f - r;
  if (x < 0.f) r = 3.14159274f - r;
  return (y < 0.f) ? -r : r;
}

// ======================= main kernel =======================
__global__ __launch_bounds__(256) void geo_euler(
    const float* __restrict__ feat,
    const float* __restrict__ w44s2, const float* __restrict__ w66s2,
    const float* __restrict__ cc,
    float* __restrict__ out, int B)
{
  const int b = blockIdx.x * 256 + threadIdx.x;
  if (b >= B) return;

  // features: 22 floats, 8-byte aligned rows -> 11x float2
  float f[22];
  {
    const float2* fp = reinterpret_cast<const float2*>(feat + (size_t)b * 22);
#pragma unroll
    for (int i = 0; i < 11; ++i) { const float2 t = fp[i]; f[2 * i] = t.x; f[2 * i + 1] = t.y; }
  }
  const float* f4 = f;
  const float* f6 = f + 9;

  float q44 = 0.f, q66 = 0.f;
  float T0[5] = {}, T1[5] = {}, T2[5] = {}; // T44, T46(=T64), T66

#pragma unroll
  for (int I = 0; I < 9; ++I)
#pragma unroll
    for (int J = I; J < 9; ++J) {
      const float p = f4[I] * f4[J];
      {
        const float c = (I == J) ? (float)cw::W440.v[I * 9 + J]
                                 : (float)(cw::W440.v[I * 9 + J] + cw::W440.v[J * 9 + I]);
        if (c != 0.f) q44 = fmaf(c, p, q44);
      }
#pragma unroll
      for (int K = 0; K < 5; ++K) {
        const float c = (I == J) ? (float)cw::W442.v[(I * 9 + J) * 5 + K]
                                 : (float)(cw::W442.v[(I * 9 + J) * 5 + K] + cw::W442.v[(J * 9 + I) * 5 + K]);
        if (c != 0.f) T0[K] = fmaf(c, p, T0[K]);
      }
    }

#pragma unroll
  for (int I = 0; I < 13; ++I)
#pragma unroll
    for (int J = I; J < 13; ++J) {
      const float p = f6[I] * f6[J];
      {
        const float c = (I == J) ? (float)cw::W660.v[I * 13 + J]
                                 : (float)(cw::W660.v[I * 13 + J] + cw::W660.v[J * 13 + I]);
        if (c != 0.f) q66 = fmaf(c, p, q66);
      }
#pragma unroll
      for (int K = 0; K < 5; ++K) {
        const float c = (I == J) ? (float)cw::W662.v[(I * 13 + J) * 5 + K]
                                 : (float)(cw::W662.v[(I * 13 + J) * 5 + K] + cw::W662.v[(J * 13 + I) * 5 + K]);
        if (c != 0.f) T2[K] = fmaf(c, p, T2[K]);
      }
    }

#pragma unroll
  for (int a = 0; a < 9; ++a)
#pragma unroll
    for (int bb = 0; bb < 13; ++bb) {
      const float p = f4[a] * f6[bb];
#pragma unroll
      for (int K = 0; K < 5; ++K) {
        const float c46 = (float)cw::W462.v[(a * 13 + bb) * 5 + K];
        if (c46 != 0.f) T1[K] = fmaf(c46, p, T1[K]);
      }
    }

  // gates g_u = sigmoid(C0 * (w44s2[8+u] q44 + w66s2[8+u] q66))
  float g[8];
#pragma unroll
  for (int u = 0; u < 8; ++u) {
    const float s = 0.70710678118654752f * fmaf(w44s2[8 + u], q44, w66s2[8 + u] * q66);
    g[u] = __builtin_amdgcn_rcpf(1.f + __expf(-s));
  }

  // pair products G_uv (u<v)
  float G[28];
  {
    int idx = 0;
#pragma unroll
    for (int u = 0; u < 8; ++u)
#pragma unroll
      for (int v = u + 1; v < 8; ++v) G[idx++] = g[u] * g[v];
  }

  // S_w(pq) from precomputed weight coefficients (uniform scalar loads)
  float S[2][3];
#pragma unroll
  for (int w = 0; w < 2; ++w)
#pragma unroll
    for (int pq = 0; pq < 3; ++pq) {
      float acc = 0.f;
      const float* cp = cc + w * 84 + pq * 28;
#pragma unroll
      for (int i = 0; i < 28; ++i) acc = fmaf(cp[i], G[i], acc);
      S[w][pq] = acc;
    }

  // B_K(T_p, T_q) via av_q = C_K T_q (sparse), then dots
  float av1[3][5] = {}, av2[3][5] = {};
#pragma unroll
  for (int I = 0; I < 5; ++I)
#pragma unroll
    for (int J = 0; J < 5; ++J)
#pragma unroll
      for (int K = 0; K < 3; ++K) {
        const float c = (float)cw::W221.v[(I * 5 + J) * 3 + K];
        if (c != 0.f) {
          av1[K][I] = fmaf(c, T1[J], av1[K][I]);
          av2[K][I] = fmaf(c, T2[J], av2[K][I]);
        }
      }
  float v0[3], v1[3];
#pragma unroll
  for (int K = 0; K < 3; ++K) {
    float M0 = 0.f, M1 = 0.f, M2 = 0.f;
#pragma unroll
    for (int I = 0; I < 5; ++I) {
      M0 = fmaf(T0[I], av1[K][I], M0); // B_K(T0,T1)
      M1 = fmaf(T0[I], av2[K][I], M1); // B_K(T0,T2)
      M2 = fmaf(T1[I], av2[K][I], M2); // B_K(T1,T2)
    }
    v0[K] = fmaf(M0, S[0][0], fmaf(M1, S[0][1], M2 * S[0][2]));
    v1[K] = fmaf(M0, S[1][0], fmaf(M1, S[1][1], M2 * S[1][2]));
  }

  // Gram-Schmidt frame + Euler angles
  const float n0 = sqrtf(v0[0] * v0[0] + v0[1] * v0[1] + v0[2] * v0[2]);
  const float i0 = __builtin_amdgcn_rcpf(fmaxf(n0, 1e-6f));
  const float z0 = v0[0] * i0, z1 = v0[1] * i0, z2 = v0[2] * i0;
  const float dot = z0 * v1[0] + z1 * v1[1] + z2 * v1[2];
  const float xv0 = v1[0] - dot * z0, xv1 = v1[1] - dot * z1, xv2 = v1[2] - dot * z2;
  const float nx = sqrtf(xv0 * xv0 + xv1 * xv1 + xv2 * xv2);
  const float ix = __builtin_amdgcn_rcpf(fmaxf(nx, 1e-6f));
  const float x0 = xv0 * ix, x1 = xv1 * ix, x2 = xv2 * ix;
  const float y0 = z1 * x2 - z2 * x1;
  const float y1 = z2 * x0 - z0 * x2;
  const float y2 = z0 * x1 - z1 * x0;

  const float r22 = fminf(fmaxf(z2, -1.f), 1.f);
  const float sb = sqrtf(fmaxf(1.f - r22 * r22, 0.f)); // |sin(acos r22)|
  const float beta = fatan2(sb, r22);                  // acos(r22)
  const bool safe = sb > 1e-6f;
  const float alpha = safe ? fatan2(z1, z0) : 0.f;
  const float gamma = safe ? fatan2(y2, -x2) : fatan2(-y0, y1);

  out[b] = alpha;
  out[B + b] = beta;
  out[2 * (size_t)B + b] = gamma;
  float* Ro = out + 3 * (size_t)B + (size_t)b * 9;
  Ro[0] = x0; Ro[1] = y0; Ro[2] = z0;
  Ro[3] = x1; Ro[4] = y1; Ro[5] = z1;
  Ro[6] = x2; Ro[7] = y2; Ro[8] = z2;
}

extern "C" void kernel_launch(void* const* d_in, const int* in_sizes, int n_in,
                              void* d_out, int out_size, void* d_ws, size_t ws_size,
                              hipStream_t stream) {
  (void)n_in; (void)out_size; (void)ws_size;
  const float* feat  = (const float*)d_in[0];
  const float* w44s2 = (const float*)d_in[3];
  const float* w66s2 = (const float*)d_in[4];
  const float* w44t  = (const float*)d_in[7];
  const float* w46t  = (const float*)d_in[8];
  const float* w64t  = (const float*)d_in[9];
  const float* w66t  = (const float*)d_in[10];
  const float* wtt   = (const float*)d_in[16];
  float* out = (float*)d_out;
  float* cc = (float*)d_ws; // 168 floats of weight-only coefficients
  const int B = in_sizes[0] / 22;
  precoef<<<1, 256, 0, stream>>>(w44t, w46t, w64t, w66t, wtt, cc);
  geo_euler<<<(B + 255) / 256, 256, 0, stream>>>(feat, w44s2, w66s2, cc, out, B);
}